// Round 1
// baseline (242.598 us; speedup 1.0000x reference)
//
#include <hip/hip_runtime.h>
#include <math.h>

// Problem constants (B,T,E,H fixed by setup_inputs).
constexpr int B_ = 8, T_ = 2048, E_ = 1024, H_ = 64;
constexpr long BT = (long)B_ * T_;   // 16384 rows

typedef __attribute__((ext_vector_type(8))) short bf16x8;   // 8 bf16 (4 VGPRs)
typedef __attribute__((ext_vector_type(4))) float f32x4;    // MFMA 16x16 acc

__device__ inline unsigned short bf16_rne(float f) {
    union { float f; unsigned u; } v; v.f = f;
    unsigned u = v.u + (0x7FFFu + ((v.u >> 16) & 1u));
    return (unsigned short)(u >> 16);
}
__device__ inline unsigned pack_bf16x2(float lo, float hi) {
    return (unsigned)bf16_rne(lo) | ((unsigned)bf16_rne(hi) << 16);
}

// Async global->LDS DMA, 16B per lane. LDS dest = wave-uniform base +
// lane*16 (HW requirement); global addr may be fully lane-divergent.
__device__ inline void load_lds16(const void* g, void* l) {
    __builtin_amdgcn_global_load_lds(
        (const __attribute__((address_space(1))) void*)(uintptr_t)g,
        (__attribute__((address_space(3))) void*)(unsigned)(uintptr_t)l,
        16, 0, 0);
}

constexpr float QS = 0.18033688011112042f;   // H^-0.5 * log2(e), folded into Wq

// ====================================================================
// Kernel 0: build B-frag-ready transposed bf16 weight buffer. (R3)
// ====================================================================
__global__ __launch_bounds__(256) void wt_build_k(
    const float* __restrict__ Wk, const float* __restrict__ Wq,
    const float* __restrict__ Wv, unsigned short* __restrict__ Wt)
{
    const int d    = blockIdx.x * 256 + threadIdx.x;   // 0..24575
    const int tile = d >> 6;
    const int lq   = d & 63;
    const int quad = lq >> 4;
    const int l16  = lq & 15;
    const int kc   = tile / 12;
    const int nt   = tile - kc * 12;
    const int n    = nt * 16 + l16;

    const float* src; int col; float s = 1.0f;
    if (n < 64)       { src = Wk; col = n; }
    else if (n < 128) { src = Wq; col = n - 64; s = QS; }
    else              { src = Wv; col = n - 128; }

    const int kk0 = kc * 32 + quad * 8;
    const float* sp = src + (size_t)kk0 * H_ + col;
    unsigned p[4];
    #pragma unroll
    for (int jj = 0; jj < 4; jj++)
        p[jj] = pack_bf16x2(sp[(2 * jj) * H_] * s, sp[(2 * jj + 1) * H_] * s);
    *(uint4*)(Wt + (size_t)d * 8) = make_uint4(p[0], p[1], p[2], p[3]);
}

// ====================================================================
// Kernel 1: MFMA QKV projection, R7 (unchanged): global_load_lds
// staged x, double-buffered, chunk-XOR swizzle; Wt b-frags from L2.
// ====================================================================
__global__ __launch_bounds__(512, 4) void qkv_mfma_k(
    const float* __restrict__ x, const unsigned short* __restrict__ Wt,
    unsigned short* __restrict__ kO, unsigned short* __restrict__ qO,
    unsigned short* __restrict__ vfO)
{
    __shared__ float4 xs[2][32][16];        // 16 KB: [buf][row][chunk], swizzled
    __shared__ unsigned short VL[32][66];   // V tile staging (pad 66)

    const int t    = threadIdx.x;           // 0..511
    const int w    = t >> 6;                // 0..7
    const int l    = t & 63;
    const int l16  = l & 15;
    const int quad = l >> 4;
    const int rg   = w >> 2;                // row-group 0..1
    const int nq   = w & 3;                 // n-quarter 0..3 (3 tiles each)
    const int row0 = blockIdx.x * 32 + rg * 16;
    const int row0b = blockIdx.x * 32;

    const int rr = w * 4 + (l >> 4);        // staged row 0..31
    const int cc = l & 15;                  // LDS chunk slot
    const int gg = cc ^ (rr & 7);           // global chunk fetched (swizzle)
    const float* gsrc = x + (size_t)(row0b + rr) * E_ + gg * 4;

    const int r  = rg * 16 + l16;           // A-frag row in tile
    const int rx = r & 7;                   // swizzle key

    f32x4 acc[3];
    #pragma unroll
    for (int n = 0; n < 3; n++) acc[n] = (f32x4){0.f, 0.f, 0.f, 0.f};

    load_lds16(gsrc, &xs[0][rr][cc]);       // stage tile 0

    for (int it = 0; it < 16; ++it) {
        const int buf = it & 1;
        __syncthreads();                    // drains tile-it DMA + prev reads
        if (it + 1 < 16)
            load_lds16(gsrc + (it + 1) * 64, &xs[buf ^ 1][rr][cc]);

        #pragma unroll
        for (int kk = 0; kk < 2; ++kk) {
            const int G0 = kk * 8 + quad * 2;
            float4 fa = xs[buf][r][G0 ^ rx];
            float4 fb = xs[buf][r][(G0 + 1) ^ rx];

            const int kc = it * 2 + kk;
            const unsigned short* wpp = Wt + (size_t)(kc * 12 + nq * 3) * 512 + (size_t)l * 8;
            bf16x8 b0 = *(const bf16x8*)(wpp);
            bf16x8 b1 = *(const bf16x8*)(wpp + 512);
            bf16x8 b2 = *(const bf16x8*)(wpp + 1024);

            union { bf16x8 v; unsigned u[4]; } av;
            av.u[0] = pack_bf16x2(fa.x, fa.y);
            av.u[1] = pack_bf16x2(fa.z, fa.w);
            av.u[2] = pack_bf16x2(fb.x, fb.y);
            av.u[3] = pack_bf16x2(fb.z, fb.w);

            acc[0] = __builtin_amdgcn_mfma_f32_16x16x32_bf16(av.v, b0, acc[0], 0, 0, 0);
            acc[1] = __builtin_amdgcn_mfma_f32_16x16x32_bf16(av.v, b1, acc[1], 0, 0, 0);
            acc[2] = __builtin_amdgcn_mfma_f32_16x16x32_bf16(av.v, b2, acc[2], 0, 0, 0);
        }
    }

    // ---- epilogue part 1: k/q global stores, v -> LDS staging ----
    #pragma unroll
    for (int n = 0; n < 3; n++) {
        const int gn = nq * 3 + n;          // 0..11
        const int hb = gn * 16 + l16;
        if (gn < 4) {                       // k columns 0..63
            #pragma unroll
            for (int rr2 = 0; rr2 < 4; rr2++) {
                const int row = row0 + quad * 4 + rr2;
                kO[(size_t)row * H_ + hb] = bf16_rne(acc[n][rr2]);
            }
        } else if (gn < 8) {                // q columns 0..63 (pre-scaled)
            #pragma unroll
            for (int rr2 = 0; rr2 < 4; rr2++) {
                const int row = row0 + quad * 4 + rr2;
                qO[(size_t)row * H_ + (hb - 64)] = bf16_rne(acc[n][rr2]);
            }
        } else {                            // v -> LDS tile [key-in-tile][h]
            #pragma unroll
            for (int rr2 = 0; rr2 < 4; rr2++)
                VL[rg * 16 + quad * 4 + rr2][(gn - 8) * 16 + l16] = bf16_rne(acc[n][rr2]);
        }
    }
    __syncthreads();

    // ---- epilogue part 2: gather permuted frags, coalesced Vf store ----
    if (t < 256) {
        const int g  = t >> 6;          // h-group 0..3
        const int lf = t & 15;
        const int qf = (t >> 4) & 3;
        unsigned pk[4];
        #pragma unroll
        for (int jj = 0; jj < 4; jj++) {
            const int p0 = qf * 8 + 2 * jj;
            const int i0 = (p0 >> 1) | ((p0 & 1) << 4);
            const int p1 = p0 + 1;
            const int i1 = (p1 >> 1) | ((p1 & 1) << 4);
            pk[jj] = (unsigned)VL[i0][g * 16 + lf]
                   | ((unsigned)VL[i1][g * 16 + lf] << 16);
        }
        const int tile = blockIdx.x;    // = b*64 + kt
        *(uint4*)(vfO + ((size_t)tile * 4 + g) * 512 + (size_t)(t & 63) * 8) =
            make_uint4(pk[0], pk[1], pk[2], pk[3]);
    }
}

// ====================================================================
// Kernel 2: MFMA flash attention, R8 (byte-identical to baseline).
// ====================================================================
__global__ __launch_bounds__(256, 2) void attn_mfma(
    const unsigned short* __restrict__ q,   // bf16 [B][T][H], pre-scaled
    const unsigned short* __restrict__ k,   // bf16 [B][T][H]
    const unsigned short* __restrict__ vf,  // bf16 fragment-major
    float* __restrict__ out)
{
    __shared__ __align__(16) unsigned short KV[4][2][4096];  // 64 KB
    __shared__ unsigned short Pl[4][16 * 40];                // 5 KB

    const int t    = threadIdx.x;
    const int w    = t >> 6;
    const int l    = t & 63;
    const int l16  = l & 15;
    const int quad = l >> 4;

    const int b    = blockIdx.x & 7;
    const int qidx = blockIdx.x >> 3;
    const int qt   = (qidx & 1) ? (127 - (qidx >> 1)) : (qidx >> 1);
    const int t0   = qt * 16;
    const int nk   = t0 / 32 + 1;

    const size_t qoff = ((size_t)b * T_ + t0 + l16) * H_ + quad * 8;
    bf16x8 aq0 = *(const bf16x8*)(q + qoff);
    bf16x8 aq1 = *(const bf16x8*)(q + qoff + 32);

    f32x4 o[4];
    #pragma unroll
    for (int g = 0; g < 4; g++) o[g] = (f32x4){0.f, 0.f, 0.f, 0.f};
    float ls[4] = {0.f, 0.f, 0.f, 0.f};

    const unsigned short* kbp = k  + (size_t)b * T_ * H_;
    const unsigned short* vfb = vf + (size_t)b * 64 * 2048;
    unsigned short* Pw = &Pl[w][0];
    unsigned short* kv0 = &KV[w][0][0];
    unsigned short* kv1 = &KV[w][1][0];

    // stage tile kt into dst: 4 K-frags + 4 V-frags, 1KB each
    auto issue_tile = [&](int kt, unsigned short* dst) {
        const int kbase = kt * 32;
        const unsigned short* kp = kbp + (size_t)(kbase + l16) * H_ + quad * 8;
        load_lds16(kp,               dst + 0 * 512 + l * 8);
        load_lds16(kp + 32,          dst + 1 * 512 + l * 8);
        load_lds16(kp + 16 * H_,     dst + 2 * 512 + l * 8);
        load_lds16(kp + 16 * H_ + 32, dst + 3 * 512 + l * 8);
        const unsigned short* vp = vfb + (size_t)kt * 2048 + l * 8;
        load_lds16(vp,        dst + 4 * 512 + l * 8);
        load_lds16(vp + 512,  dst + 5 * 512 + l * 8);
        load_lds16(vp + 1024, dst + 6 * 512 + l * 8);
        load_lds16(vp + 1536, dst + 7 * 512 + l * 8);
    };

    if (w < nk) issue_tile(w, kv0);

    int it = 0;
    for (int kt = w; kt < nk; kt += 4, ++it) {
        unsigned short* cur = (it & 1) ? kv1 : kv0;
        unsigned short* nxt = (it & 1) ? kv0 : kv1;
        if (kt + 4 < nk) {
            issue_tile(kt + 4, nxt);
            asm volatile("s_waitcnt vmcnt(8)" ::: "memory");   // tile kt done
        } else {
            asm volatile("s_waitcnt vmcnt(0)" ::: "memory");
        }

        bf16x8 bk00 = *(const bf16x8*)(cur + 0 * 512 + l * 8);
        bf16x8 bk01 = *(const bf16x8*)(cur + 1 * 512 + l * 8);
        bf16x8 bk10 = *(const bf16x8*)(cur + 2 * 512 + l * 8);
        bf16x8 bk11 = *(const bf16x8*)(cur + 3 * 512 + l * 8);
        bf16x8 bv0  = *(const bf16x8*)(cur + 4 * 512 + l * 8);
        bf16x8 bv1  = *(const bf16x8*)(cur + 5 * 512 + l * 8);
        bf16x8 bv2  = *(const bf16x8*)(cur + 6 * 512 + l * 8);
        bf16x8 bv3  = *(const bf16x8*)(cur + 7 * 512 + l * 8);

        const int kbase = kt * 32;
        f32x4 s0 = (f32x4){0.f, 0.f, 0.f, 0.f};
        f32x4 s1 = (f32x4){0.f, 0.f, 0.f, 0.f};
        s0 = __builtin_amdgcn_mfma_f32_16x16x32_bf16(aq0, bk00, s0, 0, 0, 0);
        s0 = __builtin_amdgcn_mfma_f32_16x16x32_bf16(aq1, bk01, s0, 0, 0, 0);
        s1 = __builtin_amdgcn_mfma_f32_16x16x32_bf16(aq0, bk10, s1, 0, 0, 0);
        s1 = __builtin_amdgcn_mfma_f32_16x16x32_bf16(aq1, bk11, s1, 0, 0, 0);

        if (kbase + 31 > t0) {   // diagonal tile: causal mask
            const int rowb = t0 + quad * 4;
            #pragma unroll
            for (int r = 0; r < 4; r++) {
                if (kbase + l16 > rowb + r)      s0[r] = -3.0e38f;
                if (kbase + 16 + l16 > rowb + r) s1[r] = -3.0e38f;
            }
        }

        #pragma unroll
        for (int r = 0; r < 4; r++) {
            float p0 = exp2f(s0[r]);
            float p1 = exp2f(s1[r]);
            ls[r] += p0 + p1;
            *(unsigned*)(Pw + (quad * 4 + r) * 40 + 2 * l16) = pack_bf16x2(p0, p1);
        }
        asm volatile("s_waitcnt lgkmcnt(0)" ::: "memory");   // wave-local
        bf16x8 ap = *(const bf16x8*)(Pw + l16 * 40 + quad * 8);

        o[0] = __builtin_amdgcn_mfma_f32_16x16x32_bf16(ap, bv0, o[0], 0, 0, 0);
        o[1] = __builtin_amdgcn_mfma_f32_16x16x32_bf16(ap, bv1, o[1], 0, 0, 0);
        o[2] = __builtin_amdgcn_mfma_f32_16x16x32_bf16(ap, bv2, o[2], 0, 0, 0);
        o[3] = __builtin_amdgcn_mfma_f32_16x16x32_bf16(ap, bv3, o[3], 0, 0, 0);
    }

    // ---- once-per-wave lsum row reduction (16-lane groups) ----
    #pragma unroll
    for (int r = 0; r < 4; r++) {
        float s = ls[r];
        s += __shfl_xor(s, 1);
        s += __shfl_xor(s, 2);
        s += __shfl_xor(s, 4);
        s += __shfl_xor(s, 8);
        ls[r] = s;
    }

    // ---- merge: re-alias KV region (all waves at vmcnt(0) past loop) ----
    __syncthreads();
    float* otb = (float*)&KV[0][0][0];          // Ot[w][16][68] floats
    float* lsW = otb + 4 * 16 * 68;             // + lsW[4][16]
    if (l16 == 0) {
        #pragma unroll
        for (int r = 0; r < 4; r++) lsW[w * 16 + quad * 4 + r] = ls[r];
    }
    #pragma unroll
    for (int g = 0; g < 4; g++)
        #pragma unroll
        for (int r = 0; r < 4; r++)
            otb[((w * 16) + quad * 4 + r) * 68 + g * 16 + l16] = o[g][r];
    __syncthreads();

    {
        const int col = w * 16 + l16;
        #pragma unroll
        for (int r = 0; r < 4; r++) {
            const int row = quad * 4 + r;
            float L  = lsW[0 * 16 + row] + lsW[1 * 16 + row]
                     + lsW[2 * 16 + row] + lsW[3 * 16 + row];
            float sv = otb[(0 * 16 + row) * 68 + col] + otb[(1 * 16 + row) * 68 + col]
                     + otb[(2 * 16 + row) * 68 + col] + otb[(3 * 16 + row) * 68 + col];
            out[((size_t)b * T_ + t0 + row) * H_ + col] = sv / L;
        }
    }
}

// ====================================================================
// MEASUREMENT ROUND (R9): attn_mfma launched 4x back-to-back
// (idempotent: pure overwrite of out from q/k/vf). dur_us delta vs
// baseline 147.9 = 3 x T_attn (+ ~5us extra launch gaps). If attn
// >= ~41us per dispatch it will also surface in rocprof top-5 with
// real MfmaUtil/VALUBusy/Occupancy/bank-conflict counters. Kernels
// themselves are byte-identical to the 147.9us baseline.
// ====================================================================
extern "C" void kernel_launch(void* const* d_in, const int* in_sizes, int n_in,
                              void* d_out, int out_size, void* d_ws, size_t ws_size,
                              hipStream_t stream)
{
    const float* x  = (const float*)d_in[0];
    const float* Wk = (const float*)d_in[1];
    const float* Wq = (const float*)d_in[2];
    const float* Wv = (const float*)d_in[3];

    // workspace: Wt (384KB) | k | q | vf (bf16, 2MB each)
    unsigned short* wt    = (unsigned short*)d_ws;
    unsigned short* kbuf  = wt + 24576 * 8;
    unsigned short* qbuf  = kbuf + BT * H_;
    unsigned short* vfbuf = qbuf + BT * H_;
    float* outp = (float*)d_out;

    wt_build_k<<<96, 256, 0, stream>>>(Wk, Wq, Wv, wt);
    qkv_mfma_k<<<(B_ * T_) / 32, 512, 0, stream>>>(x, wt, kbuf, qbuf, vfbuf);
    for (int rep = 0; rep < 4; ++rep)
        attn_mfma<<<B_ * 128, 256, 0, stream>>>(qbuf, kbuf, vfbuf, outp);
}

// Round 2
// 207.319 us; speedup vs baseline: 1.1702x; 1.1702x over previous
//
#include <hip/hip_runtime.h>
#include <math.h>

// Problem constants (B,T,E,H fixed by setup_inputs).
constexpr int B_ = 8, T_ = 2048, E_ = 1024, H_ = 64;
constexpr long BT = (long)B_ * T_;   // 16384 rows

typedef __attribute__((ext_vector_type(8))) short bf16x8;   // 8 bf16 (4 VGPRs)
typedef __attribute__((ext_vector_type(4))) float f32x4;    // MFMA 16x16 acc

__device__ inline unsigned short bf16_rne(float f) {
    union { float f; unsigned u; } v; v.f = f;
    unsigned u = v.u + (0x7FFFu + ((v.u >> 16) & 1u));
    return (unsigned short)(u >> 16);
}
__device__ inline unsigned pack_bf16x2(float lo, float hi) {
    return (unsigned)bf16_rne(lo) | ((unsigned)bf16_rne(hi) << 16);
}

// Async global->LDS DMA, 16B per lane. LDS dest = wave-uniform base +
// lane*16 (HW requirement); global addr may be fully lane-divergent.
__device__ inline void load_lds16(const void* g, void* l) {
    __builtin_amdgcn_global_load_lds(
        (const __attribute__((address_space(1))) void*)(uintptr_t)g,
        (__attribute__((address_space(3))) void*)(unsigned)(uintptr_t)l,
        16, 0, 0);
}

constexpr float QS = 0.18033688011112042f;   // H^-0.5 * log2(e), folded into Wq

// ====================================================================
// Kernel 0: build B-frag-ready transposed bf16 weight buffer. (R3)
// ====================================================================
__global__ __launch_bounds__(256) void wt_build_k(
    const float* __restrict__ Wk, const float* __restrict__ Wq,
    const float* __restrict__ Wv, unsigned short* __restrict__ Wt)
{
    const int d    = blockIdx.x * 256 + threadIdx.x;   // 0..24575
    const int tile = d >> 6;
    const int lq   = d & 63;
    const int quad = lq >> 4;
    const int l16  = lq & 15;
    const int kc   = tile / 12;
    const int nt   = tile - kc * 12;
    const int n    = nt * 16 + l16;

    const float* src; int col; float s = 1.0f;
    if (n < 64)       { src = Wk; col = n; }
    else if (n < 128) { src = Wq; col = n - 64; s = QS; }
    else              { src = Wv; col = n - 128; }

    const int kk0 = kc * 32 + quad * 8;
    const float* sp = src + (size_t)kk0 * H_ + col;
    unsigned p[4];
    #pragma unroll
    for (int jj = 0; jj < 4; jj++)
        p[jj] = pack_bf16x2(sp[(2 * jj) * H_] * s, sp[(2 * jj + 1) * H_] * s);
    *(uint4*)(Wt + (size_t)d * 8) = make_uint4(p[0], p[1], p[2], p[3]);
}

// ====================================================================
// Kernel 1: MFMA QKV projection, R7 structure. MEASUREMENT: body
// repeated QKV_REP times internally (idempotent; asm memory clobber
// defeats cross-rep CSE). dur = QKV_REP x T_qkv -> surfaces in
// rocprof top-5 with real counters if T_qkv >= ~14us.
// ====================================================================
constexpr int QKV_REP = 3;

__global__ __launch_bounds__(512, 4) void qkv_mfma_k(
    const float* __restrict__ x, const unsigned short* __restrict__ Wt,
    unsigned short* __restrict__ kO, unsigned short* __restrict__ qO,
    unsigned short* __restrict__ vfO)
{
    __shared__ float4 xs[2][32][16];        // 16 KB: [buf][row][chunk], swizzled
    __shared__ unsigned short VL[32][66];   // V tile staging (pad 66)

    const int t    = threadIdx.x;           // 0..511
    const int w    = t >> 6;                // 0..7
    const int l    = t & 63;
    const int l16  = l & 15;
    const int quad = l >> 4;
    const int rg   = w >> 2;                // row-group 0..1
    const int nq   = w & 3;                 // n-quarter 0..3 (3 tiles each)
    const int row0 = blockIdx.x * 32 + rg * 16;
    const int row0b = blockIdx.x * 32;

    const int rr = w * 4 + (l >> 4);        // staged row 0..31
    const int cc = l & 15;                  // LDS chunk slot
    const int gg = cc ^ (rr & 7);           // global chunk fetched (swizzle)
    const float* gsrc = x + (size_t)(row0b + rr) * E_ + gg * 4;

    const int r  = rg * 16 + l16;           // A-frag row in tile
    const int rx = r & 7;                   // swizzle key

    for (int rep = 0; rep < QKV_REP; ++rep) {
        asm volatile("" ::: "memory");      // block cross-rep value reuse

        f32x4 acc[3];
        #pragma unroll
        for (int n = 0; n < 3; n++) acc[n] = (f32x4){0.f, 0.f, 0.f, 0.f};

        load_lds16(gsrc, &xs[0][rr][cc]);       // stage tile 0

        for (int it = 0; it < 16; ++it) {
            const int buf = it & 1;
            __syncthreads();                    // drains tile-it DMA + prev reads
            if (it + 1 < 16)
                load_lds16(gsrc + (it + 1) * 64, &xs[buf ^ 1][rr][cc]);

            #pragma unroll
            for (int kk = 0; kk < 2; ++kk) {
                const int G0 = kk * 8 + quad * 2;
                float4 fa = xs[buf][r][G0 ^ rx];
                float4 fb = xs[buf][r][(G0 + 1) ^ rx];

                const int kc = it * 2 + kk;
                const unsigned short* wpp = Wt + (size_t)(kc * 12 + nq * 3) * 512 + (size_t)l * 8;
                bf16x8 b0 = *(const bf16x8*)(wpp);
                bf16x8 b1 = *(const bf16x8*)(wpp + 512);
                bf16x8 b2 = *(const bf16x8*)(wpp + 1024);

                union { bf16x8 v; unsigned u[4]; } av;
                av.u[0] = pack_bf16x2(fa.x, fa.y);
                av.u[1] = pack_bf16x2(fa.z, fa.w);
                av.u[2] = pack_bf16x2(fb.x, fb.y);
                av.u[3] = pack_bf16x2(fb.z, fb.w);

                acc[0] = __builtin_amdgcn_mfma_f32_16x16x32_bf16(av.v, b0, acc[0], 0, 0, 0);
                acc[1] = __builtin_amdgcn_mfma_f32_16x16x32_bf16(av.v, b1, acc[1], 0, 0, 0);
                acc[2] = __builtin_amdgcn_mfma_f32_16x16x32_bf16(av.v, b2, acc[2], 0, 0, 0);
            }
        }

        // ---- epilogue part 1: k/q global stores, v -> LDS staging ----
        #pragma unroll
        for (int n = 0; n < 3; n++) {
            const int gn = nq * 3 + n;          // 0..11
            const int hb = gn * 16 + l16;
            if (gn < 4) {                       // k columns 0..63
                #pragma unroll
                for (int rr2 = 0; rr2 < 4; rr2++) {
                    const int row = row0 + quad * 4 + rr2;
                    kO[(size_t)row * H_ + hb] = bf16_rne(acc[n][rr2]);
                }
            } else if (gn < 8) {                // q columns 0..63 (pre-scaled)
                #pragma unroll
                for (int rr2 = 0; rr2 < 4; rr2++) {
                    const int row = row0 + quad * 4 + rr2;
                    qO[(size_t)row * H_ + (hb - 64)] = bf16_rne(acc[n][rr2]);
                }
            } else {                            // v -> LDS tile [key-in-tile][h]
                #pragma unroll
                for (int rr2 = 0; rr2 < 4; rr2++)
                    VL[rg * 16 + quad * 4 + rr2][(gn - 8) * 16 + l16] = bf16_rne(acc[n][rr2]);
            }
        }
        __syncthreads();

        // ---- epilogue part 2: gather permuted frags, coalesced Vf store ----
        if (t < 256) {
            const int g  = t >> 6;          // h-group 0..3
            const int lf = t & 15;
            const int qf = (t >> 4) & 3;
            unsigned pk[4];
            #pragma unroll
            for (int jj = 0; jj < 4; jj++) {
                const int p0 = qf * 8 + 2 * jj;
                const int i0 = (p0 >> 1) | ((p0 & 1) << 4);
                const int p1 = p0 + 1;
                const int i1 = (p1 >> 1) | ((p1 & 1) << 4);
                pk[jj] = (unsigned)VL[i0][g * 16 + lf]
                       | ((unsigned)VL[i1][g * 16 + lf] << 16);
            }
            const int tile = blockIdx.x;    // = b*64 + kt
            *(uint4*)(vfO + ((size_t)tile * 4 + g) * 512 + (size_t)(t & 63) * 8) =
                make_uint4(pk[0], pk[1], pk[2], pk[3]);
        }
        // rep>0: first __syncthreads of next rep's it-loop orders these
        // VL reads before next rep's VL writes (16 barriers in between).
    }
}

// ====================================================================
// Kernel 2: MFMA flash attention, R8 structure. MEASUREMENT: body
// repeated ATTN_REP times internally -> ~63us dispatch, surfaces in
// rocprof top-5 with real counters. End-of-rep __syncthreads orders
// merge-buffer reads before next rep's KV re-staging (KV re-aliased).
// ====================================================================
constexpr int ATTN_REP = 2;

__global__ __launch_bounds__(256, 2) void attn_mfma(
    const unsigned short* __restrict__ q,   // bf16 [B][T][H], pre-scaled
    const unsigned short* __restrict__ k,   // bf16 [B][T][H]
    const unsigned short* __restrict__ vf,  // bf16 fragment-major
    float* __restrict__ out)
{
    __shared__ __align__(16) unsigned short KV[4][2][4096];  // 64 KB
    __shared__ unsigned short Pl[4][16 * 40];                // 5 KB

    const int t    = threadIdx.x;
    const int w    = t >> 6;
    const int l    = t & 63;
    const int l16  = l & 15;
    const int quad = l >> 4;

    const int b    = blockIdx.x & 7;
    const int qidx = blockIdx.x >> 3;
    const int qt   = (qidx & 1) ? (127 - (qidx >> 1)) : (qidx >> 1);
    const int t0   = qt * 16;
    const int nk   = t0 / 32 + 1;

    const size_t qoff = ((size_t)b * T_ + t0 + l16) * H_ + quad * 8;
    bf16x8 aq0 = *(const bf16x8*)(q + qoff);
    bf16x8 aq1 = *(const bf16x8*)(q + qoff + 32);

    const unsigned short* kbp = k  + (size_t)b * T_ * H_;
    const unsigned short* vfb = vf + (size_t)b * 64 * 2048;
    unsigned short* Pw = &Pl[w][0];
    unsigned short* kv0 = &KV[w][0][0];
    unsigned short* kv1 = &KV[w][1][0];

    // stage tile kt into dst: 4 K-frags + 4 V-frags, 1KB each
    auto issue_tile = [&](int kt, unsigned short* dst) {
        const int kbase = kt * 32;
        const unsigned short* kp = kbp + (size_t)(kbase + l16) * H_ + quad * 8;
        load_lds16(kp,               dst + 0 * 512 + l * 8);
        load_lds16(kp + 32,          dst + 1 * 512 + l * 8);
        load_lds16(kp + 16 * H_,     dst + 2 * 512 + l * 8);
        load_lds16(kp + 16 * H_ + 32, dst + 3 * 512 + l * 8);
        const unsigned short* vp = vfb + (size_t)kt * 2048 + l * 8;
        load_lds16(vp,        dst + 4 * 512 + l * 8);
        load_lds16(vp + 512,  dst + 5 * 512 + l * 8);
        load_lds16(vp + 1024, dst + 6 * 512 + l * 8);
        load_lds16(vp + 1536, dst + 7 * 512 + l * 8);
    };

    for (int rep = 0; rep < ATTN_REP; ++rep) {
        asm volatile("" ::: "memory");      // block cross-rep value reuse

        f32x4 o[4];
        #pragma unroll
        for (int g = 0; g < 4; g++) o[g] = (f32x4){0.f, 0.f, 0.f, 0.f};
        float ls[4] = {0.f, 0.f, 0.f, 0.f};

        if (w < nk) issue_tile(w, kv0);

        int it = 0;
        for (int kt = w; kt < nk; kt += 4, ++it) {
            unsigned short* cur = (it & 1) ? kv1 : kv0;
            unsigned short* nxt = (it & 1) ? kv0 : kv1;
            if (kt + 4 < nk) {
                issue_tile(kt + 4, nxt);
                asm volatile("s_waitcnt vmcnt(8)" ::: "memory");   // tile kt done
            } else {
                asm volatile("s_waitcnt vmcnt(0)" ::: "memory");
            }

            bf16x8 bk00 = *(const bf16x8*)(cur + 0 * 512 + l * 8);
            bf16x8 bk01 = *(const bf16x8*)(cur + 1 * 512 + l * 8);
            bf16x8 bk10 = *(const bf16x8*)(cur + 2 * 512 + l * 8);
            bf16x8 bk11 = *(const bf16x8*)(cur + 3 * 512 + l * 8);
            bf16x8 bv0  = *(const bf16x8*)(cur + 4 * 512 + l * 8);
            bf16x8 bv1  = *(const bf16x8*)(cur + 5 * 512 + l * 8);
            bf16x8 bv2  = *(const bf16x8*)(cur + 6 * 512 + l * 8);
            bf16x8 bv3  = *(const bf16x8*)(cur + 7 * 512 + l * 8);

            const int kbase = kt * 32;
            f32x4 s0 = (f32x4){0.f, 0.f, 0.f, 0.f};
            f32x4 s1 = (f32x4){0.f, 0.f, 0.f, 0.f};
            s0 = __builtin_amdgcn_mfma_f32_16x16x32_bf16(aq0, bk00, s0, 0, 0, 0);
            s0 = __builtin_amdgcn_mfma_f32_16x16x32_bf16(aq1, bk01, s0, 0, 0, 0);
            s1 = __builtin_amdgcn_mfma_f32_16x16x32_bf16(aq0, bk10, s1, 0, 0, 0);
            s1 = __builtin_amdgcn_mfma_f32_16x16x32_bf16(aq1, bk11, s1, 0, 0, 0);

            if (kbase + 31 > t0) {   // diagonal tile: causal mask
                const int rowb = t0 + quad * 4;
                #pragma unroll
                for (int r = 0; r < 4; r++) {
                    if (kbase + l16 > rowb + r)      s0[r] = -3.0e38f;
                    if (kbase + 16 + l16 > rowb + r) s1[r] = -3.0e38f;
                }
            }

            #pragma unroll
            for (int r = 0; r < 4; r++) {
                float p0 = exp2f(s0[r]);
                float p1 = exp2f(s1[r]);
                ls[r] += p0 + p1;
                *(unsigned*)(Pw + (quad * 4 + r) * 40 + 2 * l16) = pack_bf16x2(p0, p1);
            }
            asm volatile("s_waitcnt lgkmcnt(0)" ::: "memory");   // wave-local
            bf16x8 ap = *(const bf16x8*)(Pw + l16 * 40 + quad * 8);

            o[0] = __builtin_amdgcn_mfma_f32_16x16x32_bf16(ap, bv0, o[0], 0, 0, 0);
            o[1] = __builtin_amdgcn_mfma_f32_16x16x32_bf16(ap, bv1, o[1], 0, 0, 0);
            o[2] = __builtin_amdgcn_mfma_f32_16x16x32_bf16(ap, bv2, o[2], 0, 0, 0);
            o[3] = __builtin_amdgcn_mfma_f32_16x16x32_bf16(ap, bv3, o[3], 0, 0, 0);
        }

        // ---- once-per-wave lsum row reduction (16-lane groups) ----
        #pragma unroll
        for (int r = 0; r < 4; r++) {
            float s = ls[r];
            s += __shfl_xor(s, 1);
            s += __shfl_xor(s, 2);
            s += __shfl_xor(s, 4);
            s += __shfl_xor(s, 8);
            ls[r] = s;
        }

        // ---- merge: re-alias KV region (all waves at vmcnt(0) past loop) ----
        __syncthreads();
        float* otb = (float*)&KV[0][0][0];          // Ot[w][16][68] floats
        float* lsW = otb + 4 * 16 * 68;             // + lsW[4][16]
        if (l16 == 0) {
            #pragma unroll
            for (int r = 0; r < 4; r++) lsW[w * 16 + quad * 4 + r] = ls[r];
        }
        #pragma unroll
        for (int g = 0; g < 4; g++)
            #pragma unroll
            for (int r = 0; r < 4; r++)
                otb[((w * 16) + quad * 4 + r) * 68 + g * 16 + l16] = o[g][r];
        __syncthreads();

        {
            const int col = w * 16 + l16;
            #pragma unroll
            for (int r = 0; r < 4; r++) {
                const int row = quad * 4 + r;
                float L  = lsW[0 * 16 + row] + lsW[1 * 16 + row]
                         + lsW[2 * 16 + row] + lsW[3 * 16 + row];
                float sv = otb[(0 * 16 + row) * 68 + col] + otb[(1 * 16 + row) * 68 + col]
                         + otb[(2 * 16 + row) * 68 + col] + otb[(3 * 16 + row) * 68 + col];
                out[((size_t)b * T_ + t0 + row) * H_ + col] = sv / L;
            }
        }
        // order merge-buffer reads before next rep's KV re-staging
        __syncthreads();
    }
}

// ====================================================================
// MEASUREMENT ROUND (R10): qkv x3 internal, attn x2 internal.
// Delta math: dur ~= 173 + 2*T_qkv (attn known 31.6 from R9).
// Both kernels cross the 41us fill threshold -> real counters in
// top-5. Kernels otherwise byte-identical to the 147.9us baseline.
// ====================================================================
extern "C" void kernel_launch(void* const* d_in, const int* in_sizes, int n_in,
                              void* d_out, int out_size, void* d_ws, size_t ws_size,
                              hipStream_t stream)
{
    const float* x  = (const float*)d_in[0];
    const float* Wk = (const float*)d_in[1];
    const float* Wq = (const float*)d_in[2];
    const float* Wv = (const float*)d_in[3];

    // workspace: Wt (384KB) | k | q | vf (bf16, 2MB each)
    unsigned short* wt    = (unsigned short*)d_ws;
    unsigned short* kbuf  = wt + 24576 * 8;
    unsigned short* qbuf  = kbuf + BT * H_;
    unsigned short* vfbuf = qbuf + BT * H_;
    float* outp = (float*)d_out;

    wt_build_k<<<96, 256, 0, stream>>>(Wk, Wq, Wv, wt);
    qkv_mfma_k<<<(B_ * T_) / 32, 512, 0, stream>>>(x, wt, kbuf, qbuf, vfbuf);
    attn_mfma<<<B_ * 128, 256, 0, stream>>>(qbuf, kbuf, vfbuf, outp);
}

// Round 3
// 149.265 us; speedup vs baseline: 1.6253x; 1.3889x over previous
//
#include <hip/hip_runtime.h>
#include <math.h>

// Problem constants (B,T,E,H fixed by setup_inputs).
constexpr int B_ = 8, T_ = 2048, E_ = 1024, H_ = 64;
constexpr long BT = (long)B_ * T_;   // 16384 rows

typedef __attribute__((ext_vector_type(8))) short bf16x8;   // 8 bf16 (4 VGPRs)
typedef __attribute__((ext_vector_type(4))) float f32x4;    // MFMA 16x16 acc

__device__ inline unsigned short bf16_rne(float f) {
    union { float f; unsigned u; } v; v.f = f;
    unsigned u = v.u + (0x7FFFu + ((v.u >> 16) & 1u));
    return (unsigned short)(u >> 16);
}
// HW packed fp32->bf16 RNE: 1 VALU inst vs ~6 for the bit-twiddle pair.
__device__ inline unsigned pack_bf16x2(float lo, float hi) {
    unsigned r;
    asm("v_cvt_pk_bf16_f32 %0, %1, %2" : "=v"(r) : "v"(lo), "v"(hi));
    return r;
}

// Async global->LDS DMA, 16B per lane. LDS dest = wave-uniform base +
// lane*16 (HW requirement); global addr may be fully lane-divergent.
__device__ inline void load_lds16(const void* g, void* l) {
    __builtin_amdgcn_global_load_lds(
        (const __attribute__((address_space(1))) void*)(uintptr_t)g,
        (__attribute__((address_space(3))) void*)(unsigned)(uintptr_t)l,
        16, 0, 0);
}

constexpr float QS = 0.18033688011112042f;   // H^-0.5 * log2(e), folded into Wq

// ====================================================================
// Kernel 0: build B-frag-ready transposed bf16 weight buffer. (R3)
// ====================================================================
__global__ __launch_bounds__(256) void wt_build_k(
    const float* __restrict__ Wk, const float* __restrict__ Wq,
    const float* __restrict__ Wv, unsigned short* __restrict__ Wt)
{
    const int d    = blockIdx.x * 256 + threadIdx.x;   // 0..24575
    const int tile = d >> 6;
    const int lq   = d & 63;
    const int quad = lq >> 4;
    const int l16  = lq & 15;
    const int kc   = tile / 12;
    const int nt   = tile - kc * 12;
    const int n    = nt * 16 + l16;

    const float* src; int col; float s = 1.0f;
    if (n < 64)       { src = Wk; col = n; }
    else if (n < 128) { src = Wq; col = n - 64; s = QS; }
    else              { src = Wv; col = n - 128; }

    const int kk0 = kc * 32 + quad * 8;
    const float* sp = src + (size_t)kk0 * H_ + col;
    unsigned p[4];
    #pragma unroll
    for (int jj = 0; jj < 4; jj++)
        p[jj] = pack_bf16x2(sp[(2 * jj) * H_] * s, sp[(2 * jj + 1) * H_] * s);
    *(uint4*)(Wt + (size_t)d * 8) = make_uint4(p[0], p[1], p[2], p[3]);
}

// ====================================================================
// Kernel 1: MFMA QKV projection. R11: inner-loop fp32->bf16 pack now
// uses v_cvt_pk_bf16_f32 (was ~6-inst bit-twiddle; R10 counters:
// VALUBusy 31.6% vs MfmaUtil 10.4% -> pack was the VALU hog).
// Structure otherwise R7: global_load_lds staged x, double-buffered,
// chunk-XOR swizzle; Wt b-frags from L2.
// ====================================================================
__global__ __launch_bounds__(512, 4) void qkv_mfma_k(
    const float* __restrict__ x, const unsigned short* __restrict__ Wt,
    unsigned short* __restrict__ kO, unsigned short* __restrict__ qO,
    unsigned short* __restrict__ vfO)
{
    __shared__ float4 xs[2][32][16];        // 16 KB: [buf][row][chunk], swizzled
    __shared__ unsigned short VL[32][66];   // V tile staging (pad 66)

    const int t    = threadIdx.x;           // 0..511
    const int w    = t >> 6;                // 0..7
    const int l    = t & 63;
    const int l16  = l & 15;
    const int quad = l >> 4;
    const int rg   = w >> 2;                // row-group 0..1
    const int nq   = w & 3;                 // n-quarter 0..3 (3 tiles each)
    const int row0 = blockIdx.x * 32 + rg * 16;
    const int row0b = blockIdx.x * 32;

    const int rr = w * 4 + (l >> 4);        // staged row 0..31
    const int cc = l & 15;                  // LDS chunk slot
    const int gg = cc ^ (rr & 7);           // global chunk fetched (swizzle)
    const float* gsrc = x + (size_t)(row0b + rr) * E_ + gg * 4;

    const int r  = rg * 16 + l16;           // A-frag row in tile
    const int rx = r & 7;                   // swizzle key

    f32x4 acc[3];
    #pragma unroll
    for (int n = 0; n < 3; n++) acc[n] = (f32x4){0.f, 0.f, 0.f, 0.f};

    load_lds16(gsrc, &xs[0][rr][cc]);       // stage tile 0

    for (int it = 0; it < 16; ++it) {
        const int buf = it & 1;
        __syncthreads();                    // drains tile-it DMA + prev reads
        if (it + 1 < 16)
            load_lds16(gsrc + (it + 1) * 64, &xs[buf ^ 1][rr][cc]);

        #pragma unroll
        for (int kk = 0; kk < 2; ++kk) {
            const int G0 = kk * 8 + quad * 2;
            float4 fa = xs[buf][r][G0 ^ rx];
            float4 fb = xs[buf][r][(G0 + 1) ^ rx];

            const int kc = it * 2 + kk;
            const unsigned short* wpp = Wt + (size_t)(kc * 12 + nq * 3) * 512 + (size_t)l * 8;
            bf16x8 b0 = *(const bf16x8*)(wpp);
            bf16x8 b1 = *(const bf16x8*)(wpp + 512);
            bf16x8 b2 = *(const bf16x8*)(wpp + 1024);

            union { bf16x8 v; unsigned u[4]; } av;
            av.u[0] = pack_bf16x2(fa.x, fa.y);
            av.u[1] = pack_bf16x2(fa.z, fa.w);
            av.u[2] = pack_bf16x2(fb.x, fb.y);
            av.u[3] = pack_bf16x2(fb.z, fb.w);

            acc[0] = __builtin_amdgcn_mfma_f32_16x16x32_bf16(av.v, b0, acc[0], 0, 0, 0);
            acc[1] = __builtin_amdgcn_mfma_f32_16x16x32_bf16(av.v, b1, acc[1], 0, 0, 0);
            acc[2] = __builtin_amdgcn_mfma_f32_16x16x32_bf16(av.v, b2, acc[2], 0, 0, 0);
        }
    }

    // ---- epilogue part 1: k/q global stores, v -> LDS staging ----
    #pragma unroll
    for (int n = 0; n < 3; n++) {
        const int gn = nq * 3 + n;          // 0..11
        const int hb = gn * 16 + l16;
        if (gn < 4) {                       // k columns 0..63
            #pragma unroll
            for (int rr2 = 0; rr2 < 4; rr2++) {
                const int row = row0 + quad * 4 + rr2;
                kO[(size_t)row * H_ + hb] = bf16_rne(acc[n][rr2]);
            }
        } else if (gn < 8) {                // q columns 0..63 (pre-scaled)
            #pragma unroll
            for (int rr2 = 0; rr2 < 4; rr2++) {
                const int row = row0 + quad * 4 + rr2;
                qO[(size_t)row * H_ + (hb - 64)] = bf16_rne(acc[n][rr2]);
            }
        } else {                            // v -> LDS tile [key-in-tile][h]
            #pragma unroll
            for (int rr2 = 0; rr2 < 4; rr2++)
                VL[rg * 16 + quad * 4 + rr2][(gn - 8) * 16 + l16] = bf16_rne(acc[n][rr2]);
        }
    }
    __syncthreads();

    // ---- epilogue part 2: gather permuted frags, coalesced Vf store ----
    if (t < 256) {
        const int g  = t >> 6;          // h-group 0..3
        const int lf = t & 15;
        const int qf = (t >> 4) & 3;
        unsigned pk[4];
        #pragma unroll
        for (int jj = 0; jj < 4; jj++) {
            const int p0 = qf * 8 + 2 * jj;
            const int i0 = (p0 >> 1) | ((p0 & 1) << 4);
            const int p1 = p0 + 1;
            const int i1 = (p1 >> 1) | ((p1 & 1) << 4);
            pk[jj] = (unsigned)VL[i0][g * 16 + lf]
                   | ((unsigned)VL[i1][g * 16 + lf] << 16);
        }
        const int tile = blockIdx.x;    // = b*64 + kt
        *(uint4*)(vfO + ((size_t)tile * 4 + g) * 512 + (size_t)(t & 63) * 8) =
            make_uint4(pk[0], pk[1], pk[2], pk[3]);
    }
}

// ====================================================================
// Kernel 2: MFMA flash attention, R11 rewrite: NO KV LDS staging.
// Rationale: per-batch K+Vf = 512 KB, L2-resident (b = blockIdx&7
// pins batch->XCD); R8's DMA staging burned ~12us of pure LDS BW
// (18KB/wave-iter) at 2 blocks/CU. Now K/V frags load L2->registers,
// double-buffered in two named structs (static indexing only),
// prefetch distance 1 tile, sched_barrier(0) pins the load cluster
// above the current tile's compute (defeats the R5/R6 load-sinking).
// LDS = P round-trip + merge buffers only (22.8 KB) -> 3 blocks/CU.
// ====================================================================
struct KVr { bf16x8 k00, k01, k10, k11, v0, v1, v2, v3; };

__global__ __launch_bounds__(256, 3) void attn_mfma(
    const unsigned short* __restrict__ q,   // bf16 [B][T][H], pre-scaled
    const unsigned short* __restrict__ k,   // bf16 [B][T][H]
    const unsigned short* __restrict__ vf,  // bf16 fragment-major
    float* __restrict__ out)
{
    __shared__ unsigned short Pl[4][16 * 40];   // 5 KB   P round-trip
    __shared__ float Ot[4][16][68];             // 17.4 KB merge
    __shared__ float LsW[4][16];                // 256 B

    const int t    = threadIdx.x;
    const int w    = t >> 6;
    const int l    = t & 63;
    const int l16  = l & 15;
    const int quad = l >> 4;

    const int b    = blockIdx.x & 7;
    const int qidx = blockIdx.x >> 3;
    const int qt   = (qidx & 1) ? (127 - (qidx >> 1)) : (qidx >> 1);
    const int t0   = qt * 16;
    const int nk   = t0 / 32 + 1;

    const size_t qoff = ((size_t)b * T_ + t0 + l16) * H_ + quad * 8;
    bf16x8 aq0 = *(const bf16x8*)(q + qoff);
    bf16x8 aq1 = *(const bf16x8*)(q + qoff + 32);

    f32x4 o[4];
    #pragma unroll
    for (int g = 0; g < 4; g++) o[g] = (f32x4){0.f, 0.f, 0.f, 0.f};
    float ls[4] = {0.f, 0.f, 0.f, 0.f};

    // per-lane base pointers (lane offsets folded in once)
    const unsigned short* kbp = k  + (size_t)b * T_ * H_ + (size_t)l16 * H_ + quad * 8;
    const unsigned short* vfb = vf + (size_t)b * 64 * 2048 + (size_t)l * 8;
    unsigned short* Pw = &Pl[w][0];

    auto LT = [&](int kt, KVr& R) {          // tile kt -> registers (L2 hits)
        const unsigned short* kp = kbp + (size_t)kt * 32 * H_;
        R.k00 = *(const bf16x8*)(kp);
        R.k01 = *(const bf16x8*)(kp + 32);
        R.k10 = *(const bf16x8*)(kp + 16 * H_);
        R.k11 = *(const bf16x8*)(kp + 16 * H_ + 32);
        const unsigned short* vp = vfb + (size_t)kt * 2048;
        R.v0 = *(const bf16x8*)(vp);
        R.v1 = *(const bf16x8*)(vp + 512);
        R.v2 = *(const bf16x8*)(vp + 1024);
        R.v3 = *(const bf16x8*)(vp + 1536);
    };

    auto COMP = [&](int kt, KVr& R) {
        f32x4 s0 = (f32x4){0.f, 0.f, 0.f, 0.f};
        f32x4 s1 = (f32x4){0.f, 0.f, 0.f, 0.f};
        s0 = __builtin_amdgcn_mfma_f32_16x16x32_bf16(aq0, R.k00, s0, 0, 0, 0);
        s0 = __builtin_amdgcn_mfma_f32_16x16x32_bf16(aq1, R.k01, s0, 0, 0, 0);
        s1 = __builtin_amdgcn_mfma_f32_16x16x32_bf16(aq0, R.k10, s1, 0, 0, 0);
        s1 = __builtin_amdgcn_mfma_f32_16x16x32_bf16(aq1, R.k11, s1, 0, 0, 0);

        const int kbase = kt * 32;
        if (kbase + 31 > t0) {   // diagonal tile: causal mask
            const int rowb = t0 + quad * 4;
            #pragma unroll
            for (int r = 0; r < 4; r++) {
                if (kbase + l16 > rowb + r)      s0[r] = -3.0e38f;
                if (kbase + 16 + l16 > rowb + r) s1[r] = -3.0e38f;
            }
        }

        #pragma unroll
        for (int r = 0; r < 4; r++) {
            float p0 = exp2f(s0[r]);
            float p1 = exp2f(s1[r]);
            ls[r] += p0 + p1;
            *(unsigned*)(Pw + (quad * 4 + r) * 40 + 2 * l16) = pack_bf16x2(p0, p1);
        }
        asm volatile("s_waitcnt lgkmcnt(0)" ::: "memory");   // wave-local P
        bf16x8 ap = *(const bf16x8*)(Pw + l16 * 40 + quad * 8);

        o[0] = __builtin_amdgcn_mfma_f32_16x16x32_bf16(ap, R.v0, o[0], 0, 0, 0);
        o[1] = __builtin_amdgcn_mfma_f32_16x16x32_bf16(ap, R.v1, o[1], 0, 0, 0);
        o[2] = __builtin_amdgcn_mfma_f32_16x16x32_bf16(ap, R.v2, o[2], 0, 0, 0);
        o[3] = __builtin_amdgcn_mfma_f32_16x16x32_bf16(ap, R.v3, o[3], 0, 0, 0);
    };

    KVr A, B;
    int kt = w;
    if (kt < nk) {
        LT(kt, A);
        while (true) {
            if (kt + 4 < nk) {
                LT(kt + 4, B);                      // prefetch next tile
                __builtin_amdgcn_sched_barrier(0);  // pin loads above compute
            }
            COMP(kt, A);
            kt += 4;
            if (kt >= nk) break;
            if (kt + 4 < nk) {
                LT(kt + 4, A);
                __builtin_amdgcn_sched_barrier(0);
            }
            COMP(kt, B);
            kt += 4;
            if (kt >= nk) break;
        }
    }

    // ---- once-per-wave lsum row reduction (16-lane groups) ----
    #pragma unroll
    for (int r = 0; r < 4; r++) {
        float s = ls[r];
        s += __shfl_xor(s, 1);
        s += __shfl_xor(s, 2);
        s += __shfl_xor(s, 4);
        s += __shfl_xor(s, 8);
        ls[r] = s;
    }

    // ---- merge across the 4 waves ----
    if (l16 == 0) {
        #pragma unroll
        for (int r = 0; r < 4; r++) LsW[w][quad * 4 + r] = ls[r];
    }
    #pragma unroll
    for (int g = 0; g < 4; g++)
        #pragma unroll
        for (int r = 0; r < 4; r++)
            Ot[w][quad * 4 + r][g * 16 + l16] = o[g][r];
    __syncthreads();

    {
        const int col = w * 16 + l16;
        #pragma unroll
        for (int r = 0; r < 4; r++) {
            const int row = quad * 4 + r;
            float L  = LsW[0][row] + LsW[1][row] + LsW[2][row] + LsW[3][row];
            float sv = Ot[0][row][col] + Ot[1][row][col]
                     + Ot[2][row][col] + Ot[3][row][col];
            out[((size_t)b * T_ + t0 + row) * H_ + col] = sv / L;
        }
    }
}

// ====================================================================
extern "C" void kernel_launch(void* const* d_in, const int* in_sizes, int n_in,
                              void* d_out, int out_size, void* d_ws, size_t ws_size,
                              hipStream_t stream)
{
    const float* x  = (const float*)d_in[0];
    const float* Wk = (const float*)d_in[1];
    const float* Wq = (const float*)d_in[2];
    const float* Wv = (const float*)d_in[3];

    // workspace: Wt (384KB) | k | q | vf (bf16, 2MB each)
    unsigned short* wt    = (unsigned short*)d_ws;
    unsigned short* kbuf  = wt + 24576 * 8;
    unsigned short* qbuf  = kbuf + BT * H_;
    unsigned short* vfbuf = qbuf + BT * H_;
    float* outp = (float*)d_out;

    wt_build_k<<<96, 256, 0, stream>>>(Wk, Wq, Wv, wt);
    qkv_mfma_k<<<(B_ * T_) / 32, 512, 0, stream>>>(x, wt, kbuf, qbuf, vfbuf);
    attn_mfma<<<B_ * 128, 256, 0, stream>>>(qbuf, kbuf, vfbuf, outp);
}